// Round 1
// baseline (734.692 us; speedup 1.0000x reference)
//
#include <hip/hip_runtime.h>

// SSD2d: y[b,o,h,w] = 1 - (xs[b,h,w] + k[o] - 2*c[b,o,h,w]) / 196
//   xs = 7x7 box sum of x^2 (zero-padded), k[o] = sum(w[o]^2),
//   c  = cross-correlation of x with w[o] (same padding).
// Shapes: x[8,1,384,384] f32, w[128,1,7,7] f32, y[8,128,384,384] f32.

#define BB   8
#define HH   384
#define WW   384
#define COUT 128
#define KT   49     // 7*7 taps
#define PH   3

#define TW 64       // tile width  (one wave per row)
#define TH 4        // tile height (4 waves per block)
#define HALO_W (TW + 6)   // 70
#define HALO_H (TH + 6)   // 10
#define LDS_STRIDE 72

__global__ __launch_bounds__(256) void ssd2d_kernel(
    const float* __restrict__ x, const float* __restrict__ wt,
    float* __restrict__ y)
{
    __shared__ float tile[HALO_H][LDS_STRIDE];
    __shared__ float kq[COUT];   // k[o] / 196

    const int tid = threadIdx.x;
    const int w0 = blockIdx.x * TW;
    const int h0 = blockIdx.y * TH;
    const int b  = blockIdx.z;

    // ---- stage x tile + halo into LDS (zero-padded) ----
    const float* xb = x + (size_t)b * (HH * WW);
    for (int idx = tid; idx < HALO_H * HALO_W; idx += 256) {
        int r = idx / HALO_W;
        int c = idx - r * HALO_W;
        int hh = h0 - PH + r;
        int ww = w0 - PH + c;
        float v = 0.0f;
        if (hh >= 0 && hh < HH && ww >= 0 && ww < WW) v = xb[hh * WW + ww];
        tile[r][c] = v;
    }
    // ---- per-block k[o]/196 (25 KB weights are L1/L2 resident) ----
    if (tid < COUT) {
        const float* wo = wt + tid * KT;
        float s = 0.0f;
        #pragma unroll
        for (int t = 0; t < KT; ++t) { float v = wo[t]; s = fmaf(v, v, s); }
        kq[tid] = s * (1.0f / 196.0f);
    }
    __syncthreads();

    const int tx = tid & 63;   // wave-contiguous along w -> coalesced stores
    const int ty = tid >> 6;

    // ---- 7x7 patch into registers (49 VGPRs), conflict-free LDS reads ----
    float p[KT];
    #pragma unroll
    for (int dy = 0; dy < 7; ++dy)
        #pragma unroll
        for (int dx = 0; dx < 7; ++dx)
            p[dy * 7 + dx] = tile[ty + dy][tx + dx];

    float xs = 0.0f;
    #pragma unroll
    for (int t = 0; t < KT; ++t) xs = fmaf(p[t], p[t], xs);
    const float base = 1.0f - xs * (1.0f / 196.0f);

    float* yb = y + ((size_t)b * COUT) * (HH * WW)
                  + (size_t)(h0 + ty) * WW + (w0 + tx);

    // ---- main loop over output channels ----
    for (int o = 0; o < COUT; ++o) {
        const float* wo = wt + o * KT;   // wave-uniform -> s_load path
        float a0 = 0.0f, a1 = 0.0f, a2 = 0.0f, a3 = 0.0f;
        #pragma unroll
        for (int t = 0; t < 48; t += 4) {
            a0 = fmaf(p[t + 0], wo[t + 0], a0);
            a1 = fmaf(p[t + 1], wo[t + 1], a1);
            a2 = fmaf(p[t + 2], wo[t + 2], a2);
            a3 = fmaf(p[t + 3], wo[t + 3], a3);
        }
        a0 = fmaf(p[48], wo[48], a0);
        float acc = (a0 + a1) + (a2 + a3);
        // y = base - k/196 + acc * (2/196)
        float val = fmaf(acc, (1.0f / 98.0f), base - kq[o]);
        yb[(size_t)o * (HH * WW)] = val;
    }
}

extern "C" void kernel_launch(void* const* d_in, const int* in_sizes, int n_in,
                              void* d_out, int out_size, void* d_ws, size_t ws_size,
                              hipStream_t stream) {
    const float* x  = (const float*)d_in[0];
    const float* wt = (const float*)d_in[1];
    float* y = (float*)d_out;
    dim3 grid(WW / TW, HH / TH, BB);   // 6 x 96 x 8 = 4608 blocks
    ssd2d_kernel<<<grid, dim3(256), 0, stream>>>(x, wt, y);
}